// Round 1
// baseline (2267.037 us; speedup 1.0000x reference)
//
#include <hip/hip_runtime.h>

#define INDIM 256
#define HID 128
#define OUTD 64

// ---------------- degree / dinv ----------------
__global__ void k_init_deg(float* __restrict__ deg, int n) {
    int i = blockIdx.x * blockDim.x + threadIdx.x;
    if (i < n) deg[i] = 1.0f;  // self-loop
}

__global__ void k_count_deg(const int* __restrict__ dst, float* __restrict__ deg, int E) {
    int e = blockIdx.x * blockDim.x + threadIdx.x;
    if (e < E) atomicAdd(&deg[dst[e]], 1.0f);
}

__global__ void k_dinv(float* __restrict__ deg, int n) {
    int i = blockIdx.x * blockDim.x + threadIdx.x;
    if (i < n) deg[i] = rsqrtf(deg[i]);   // deg >= 1 always (self-loop)
}

// ---------------- fp32 GEMM + epilogue ----------------
// C = X[M,K] @ W[K,BN]; writes XW = C and INIT = bias + C * dinv[row]^2
// (INIT seeds the aggregation output with the self-loop term + bias.)
// 256 threads, 8x8 microtile: (BM/8)*(BN/8) == 256.
template <int BM, int BN, int K>
__global__ __launch_bounds__(256) void k_gemm_init(
    const float* __restrict__ X, const float* __restrict__ W,
    const float* __restrict__ bias, const float* __restrict__ dinv,
    float* __restrict__ XW, float* __restrict__ INIT, int M)
{
    constexpr int BK = 32;
    constexpr int NT = 256;
    static_assert((BM / 8) * (BN / 8) == NT, "thread tile mismatch");

    __shared__ __align__(16) float As[BK][BM + 4];  // transposed A tile
    __shared__ __align__(16) float Bs[BK][BN + 4];

    const int tid   = threadIdx.x;
    const int col_t = tid % (BN / 8);
    const int row_t = tid / (BN / 8);
    const int rb    = blockIdx.x * BM;

    float acc[8][8];
#pragma unroll
    for (int i = 0; i < 8; i++)
#pragma unroll
        for (int j = 0; j < 8; j++) acc[i][j] = 0.0f;

    for (int kt = 0; kt < K; kt += BK) {
        // ---- A tile: [BM][BK] -> As transposed [BK][BM] ----
        constexpr int ACH = BM * BK / 4;
#pragma unroll
        for (int i = 0; i < ACH / NT; i++) {
            int ch  = tid + i * NT;
            int row = ch / (BK / 4);
            int c4  = ch % (BK / 4);
            float4 v = make_float4(0.f, 0.f, 0.f, 0.f);
            int gr = rb + row;
            if (gr < M) v = *(const float4*)(X + (long)gr * K + kt + c4 * 4);
            As[c4 * 4 + 0][row] = v.x;
            As[c4 * 4 + 1][row] = v.y;
            As[c4 * 4 + 2][row] = v.z;
            As[c4 * 4 + 3][row] = v.w;
        }
        // ---- B tile: [BK][BN] ----
        constexpr int BCH = BK * BN / 4;
#pragma unroll
        for (int i = 0; i < BCH / NT; i++) {
            int ch = tid + i * NT;
            int k  = ch / (BN / 4);
            int n4 = ch % (BN / 4);
            *(float4*)(&Bs[k][n4 * 4]) = *(const float4*)(W + (long)(kt + k) * BN + n4 * 4);
        }
        __syncthreads();

#pragma unroll
        for (int k = 0; k < BK; k++) {
            const float* ap = &As[k][row_t * 8];
            float4 a0 = *(const float4*)(ap);
            float4 a1 = *(const float4*)(ap + 4);
            const float* bp = &Bs[k][0];
            float4 b0 = *(const float4*)(bp + col_t * 4);
            float4 b1 = *(const float4*)(bp + BN / 2 + col_t * 4);
            float a[8] = {a0.x, a0.y, a0.z, a0.w, a1.x, a1.y, a1.z, a1.w};
            float b[8] = {b0.x, b0.y, b0.z, b0.w, b1.x, b1.y, b1.z, b1.w};
#pragma unroll
            for (int i = 0; i < 8; i++)
#pragma unroll
                for (int j = 0; j < 8; j++) acc[i][j] += a[i] * b[j];
        }
        __syncthreads();
    }

    // ---- epilogue ----
    float4 bias0 = *(const float4*)(bias + col_t * 4);
    float4 bias1 = *(const float4*)(bias + BN / 2 + col_t * 4);
#pragma unroll
    for (int i = 0; i < 8; i++) {
        int row = rb + row_t * 8 + i;
        if (row < M) {
            float di  = dinv[row];
            float di2 = di * di;
            float4 c0 = make_float4(acc[i][0], acc[i][1], acc[i][2], acc[i][3]);
            float4 c1 = make_float4(acc[i][4], acc[i][5], acc[i][6], acc[i][7]);
            *(float4*)(XW + (long)row * BN + col_t * 4) = c0;
            *(float4*)(XW + (long)row * BN + BN / 2 + col_t * 4) = c1;
            float4 o0 = make_float4(bias0.x + c0.x * di2, bias0.y + c0.y * di2,
                                    bias0.z + c0.z * di2, bias0.w + c0.w * di2);
            float4 o1 = make_float4(bias1.x + c1.x * di2, bias1.y + c1.y * di2,
                                    bias1.z + c1.z * di2, bias1.w + c1.w * di2);
            *(float4*)(INIT + (long)row * BN + col_t * 4) = o0;
            *(float4*)(INIT + (long)row * BN + BN / 2 + col_t * 4) = o1;
        }
    }
}

// ---------------- edge aggregation (atomic scatter-add) ----------------
// out[dst] += feat[src] * dinv[src]*dinv[dst], one thread per (edge, float4-chunk)
template <int F>
__global__ void k_agg(const int* __restrict__ src, const int* __restrict__ dst,
                      const float* __restrict__ dinv, const float* __restrict__ feat,
                      float* __restrict__ out, int E)
{
    constexpr int CH = F / 4;
    long tid = (long)blockIdx.x * blockDim.x + threadIdx.x;
    int e = (int)(tid / CH);
    int c = (int)(tid % CH);
    if (e >= E) return;
    int s = src[e], d = dst[e];
    float w = dinv[s] * dinv[d];
    float4 v = *(const float4*)(feat + (long)s * F + c * 4);
    float* o = out + (long)d * F + c * 4;
    atomicAdd(o + 0, v.x * w);
    atomicAdd(o + 1, v.y * w);
    atomicAdd(o + 2, v.z * w);
    atomicAdd(o + 3, v.w * w);
}

// ---------------- tanh ----------------
__global__ void k_tanh4(float* __restrict__ h, int n4) {
    int i = blockIdx.x * blockDim.x + threadIdx.x;
    if (i < n4) {
        float4 v = ((float4*)h)[i];
        v.x = tanhf(v.x);
        v.y = tanhf(v.y);
        v.z = tanhf(v.z);
        v.w = tanhf(v.w);
        ((float4*)h)[i] = v;
    }
}

extern "C" void kernel_launch(void* const* d_in, const int* in_sizes, int n_in,
                              void* d_out, int out_size, void* d_ws, size_t ws_size,
                              hipStream_t stream) {
    const float* x  = (const float*)d_in[0];
    const int*   ei = (const int*)d_in[1];   // int64 in reference -> int32 from harness
    const float* W1 = (const float*)d_in[2];
    const float* b1 = (const float*)d_in[3];
    const float* W2 = (const float*)d_in[4];
    const float* b2 = (const float*)d_in[5];
    float* out = (float*)d_out;

    const int M = in_sizes[0] / INDIM;   // 50000
    const int E = in_sizes[1] / 2;       // 800000
    const int* srcp = ei;
    const int* dstp = ei + E;

    // workspace: deg/dinv | xw[M*128] | h[M*128] | hw[M*64]
    float* deg = (float*)d_ws;
    float* xw  = deg + ((M + 3) & ~3);
    float* h   = xw + (long)M * HID;
    float* hw  = h + (long)M * HID;

    // degree -> dinv
    k_init_deg<<<(M + 255) / 256, 256, 0, stream>>>(deg, M);
    k_count_deg<<<(E + 255) / 256, 256, 0, stream>>>(dstp, deg, E);
    k_dinv<<<(M + 255) / 256, 256, 0, stream>>>(deg, M);

    // layer 1: xw = x@W1 ; h = b1 + xw*dinv^2 (self-loop) ; += edges ; tanh
    k_gemm_init<128, 128, INDIM><<<(M + 127) / 128, 256, 0, stream>>>(x, W1, b1, deg, xw, h, M);
    {
        long threads = (long)E * (HID / 4);
        k_agg<HID><<<(threads + 255) / 256, 256, 0, stream>>>(srcp, dstp, deg, xw, h, E);
    }
    k_tanh4<<<((M * HID / 4) + 255) / 256, 256, 0, stream>>>(h, M * HID / 4);

    // layer 2: hw = h@W2 ; out = b2 + hw*dinv^2 ; += edges
    k_gemm_init<256, 64, HID><<<(M + 255) / 256, 256, 0, stream>>>(h, W2, b2, deg, hw, out, M);
    {
        long threads = (long)E * (OUTD / 4);
        k_agg<OUTD><<<(threads + 255) / 256, 256, 0, stream>>>(srcp, dstp, deg, hw, out, E);
    }
}

// Round 2
// 396.305 us; speedup vs baseline: 5.7204x; 5.7204x over previous
//
#include <hip/hip_runtime.h>

#define INDIM 256
#define HID 128
#define OUTD 64

// =============== CSR build ===============

__global__ __launch_bounds__(256) void k_zero2(int* __restrict__ a, int* __restrict__ b, int n) {
    int i = blockIdx.x * 256 + threadIdx.x;
    if (i < n) { a[i] = 0; b[i] = 0; }
}

__global__ __launch_bounds__(256) void k_count(const int* __restrict__ dst, int* __restrict__ counts, int E) {
    int e = blockIdx.x * 256 + threadIdx.x;
    if (e < E) atomicAdd(&counts[dst[e]], 1);
}

__global__ __launch_bounds__(256) void k_breduce(const int* __restrict__ counts, int* __restrict__ bsum, int M) {
    __shared__ int s[256];
    int tid = threadIdx.x;
    int i = blockIdx.x * 256 + tid;
    s[tid] = (i < M) ? counts[i] : 0;
    __syncthreads();
#pragma unroll
    for (int off = 128; off > 0; off >>= 1) {
        if (tid < off) s[tid] += s[tid + off];
        __syncthreads();
    }
    if (tid == 0) bsum[blockIdx.x] = s[0];
}

// single-block exclusive scan of block sums (NB <= 256)
__global__ __launch_bounds__(256) void k_bscan(int* __restrict__ bsum, int NB) {
    __shared__ int s[256];
    int tid = threadIdx.x;
    int v = (tid < NB) ? bsum[tid] : 0;
    s[tid] = v;
    __syncthreads();
#pragma unroll
    for (int off = 1; off < 256; off <<= 1) {
        int t = (tid >= off) ? s[tid - off] : 0;
        __syncthreads();
        s[tid] += t;
        __syncthreads();
    }
    if (tid < NB) bsum[tid] = s[tid] - v;  // exclusive
}

// per-block inclusive scan + bsum offset -> row_start; also dinv = rsqrt(1+count)
__global__ __launch_bounds__(256) void k_scan_final(const int* __restrict__ counts, const int* __restrict__ bsum,
                                                    int* __restrict__ row_start, float* __restrict__ dinv, int M) {
    __shared__ int s[256];
    int tid = threadIdx.x;
    int i = blockIdx.x * 256 + tid;
    int v = (i < M) ? counts[i] : 0;
    s[tid] = v;
    __syncthreads();
#pragma unroll
    for (int off = 1; off < 256; off <<= 1) {
        int t = (tid >= off) ? s[tid - off] : 0;
        __syncthreads();
        s[tid] += t;
        __syncthreads();
    }
    if (i < M) {
        int excl = bsum[blockIdx.x] + s[tid] - v;
        row_start[i] = excl;
        dinv[i] = rsqrtf(1.0f + (float)v);   // deg incl. self-loop
        if (i == M - 1) row_start[M] = excl + v;
    }
}

__global__ __launch_bounds__(256) void k_fill(const int* __restrict__ src, const int* __restrict__ dst,
                                              const int* __restrict__ row_start, int* __restrict__ cursor,
                                              const float* __restrict__ dinv,
                                              int* __restrict__ edge_src, float* __restrict__ edge_w, int E) {
    int e = blockIdx.x * 256 + threadIdx.x;
    if (e >= E) return;
    int s = src[e], d = dst[e];
    int pos = row_start[d] + atomicAdd(&cursor[d], 1);
    edge_src[pos] = s;
    edge_w[pos] = dinv[s] * dinv[d];
}

// =============== fp32 GEMM + epilogue ===============
// C = X[M,K] @ W[K,BN]; writes XW = C and INIT = bias + C * dinv[row]^2
template <int BM, int BN, int K>
__global__ __launch_bounds__(256) void k_gemm_init(
    const float* __restrict__ X, const float* __restrict__ W,
    const float* __restrict__ bias, const float* __restrict__ dinv,
    float* __restrict__ XW, float* __restrict__ INIT, int M)
{
    constexpr int BK = 32;
    constexpr int NT = 256;
    static_assert((BM / 8) * (BN / 8) == NT, "thread tile mismatch");

    __shared__ __align__(16) float As[BK][BM + 4];  // transposed A tile
    __shared__ __align__(16) float Bs[BK][BN + 4];

    const int tid   = threadIdx.x;
    const int col_t = tid % (BN / 8);
    const int row_t = tid / (BN / 8);
    const int rb    = blockIdx.x * BM;

    float acc[8][8];
#pragma unroll
    for (int i = 0; i < 8; i++)
#pragma unroll
        for (int j = 0; j < 8; j++) acc[i][j] = 0.0f;

    for (int kt = 0; kt < K; kt += BK) {
        constexpr int ACH = BM * BK / 4;
#pragma unroll
        for (int i = 0; i < ACH / NT; i++) {
            int ch  = tid + i * NT;
            int row = ch / (BK / 4);
            int c4  = ch % (BK / 4);
            float4 v = make_float4(0.f, 0.f, 0.f, 0.f);
            int gr = rb + row;
            if (gr < M) v = *(const float4*)(X + (long)gr * K + kt + c4 * 4);
            As[c4 * 4 + 0][row] = v.x;
            As[c4 * 4 + 1][row] = v.y;
            As[c4 * 4 + 2][row] = v.z;
            As[c4 * 4 + 3][row] = v.w;
        }
        constexpr int BCH = BK * BN / 4;
#pragma unroll
        for (int i = 0; i < BCH / NT; i++) {
            int ch = tid + i * NT;
            int k  = ch / (BN / 4);
            int n4 = ch % (BN / 4);
            *(float4*)(&Bs[k][n4 * 4]) = *(const float4*)(W + (long)(kt + k) * BN + n4 * 4);
        }
        __syncthreads();

#pragma unroll
        for (int k = 0; k < BK; k++) {
            const float* ap = &As[k][row_t * 8];
            float4 a0 = *(const float4*)(ap);
            float4 a1 = *(const float4*)(ap + 4);
            const float* bp = &Bs[k][0];
            float4 b0 = *(const float4*)(bp + col_t * 4);
            float4 b1 = *(const float4*)(bp + BN / 2 + col_t * 4);
            float a[8] = {a0.x, a0.y, a0.z, a0.w, a1.x, a1.y, a1.z, a1.w};
            float b[8] = {b0.x, b0.y, b0.z, b0.w, b1.x, b1.y, b1.z, b1.w};
#pragma unroll
            for (int i = 0; i < 8; i++)
#pragma unroll
                for (int j = 0; j < 8; j++) acc[i][j] += a[i] * b[j];
        }
        __syncthreads();
    }

    float4 bias0 = *(const float4*)(bias + col_t * 4);
    float4 bias1 = *(const float4*)(bias + BN / 2 + col_t * 4);
#pragma unroll
    for (int i = 0; i < 8; i++) {
        int row = rb + row_t * 8 + i;
        if (row < M) {
            float di  = dinv[row];
            float di2 = di * di;
            float4 c0 = make_float4(acc[i][0], acc[i][1], acc[i][2], acc[i][3]);
            float4 c1 = make_float4(acc[i][4], acc[i][5], acc[i][6], acc[i][7]);
            *(float4*)(XW + (long)row * BN + col_t * 4) = c0;
            *(float4*)(XW + (long)row * BN + BN / 2 + col_t * 4) = c1;
            float4 o0 = make_float4(bias0.x + c0.x * di2, bias0.y + c0.y * di2,
                                    bias0.z + c0.z * di2, bias0.w + c0.w * di2);
            float4 o1 = make_float4(bias1.x + c1.x * di2, bias1.y + c1.y * di2,
                                    bias1.z + c1.z * di2, bias1.w + c1.w * di2);
            *(float4*)(INIT + (long)row * BN + col_t * 4) = o0;
            *(float4*)(INIT + (long)row * BN + BN / 2 + col_t * 4) = o1;
        }
    }
}

// =============== CSR gather-aggregation ===============
// out[n] = (TANH? tanh : id)(out[n] + sum_{e in-edges(n)} feat[edge_src[e]] * edge_w[e])
// LPN = F/4 lanes per node; each lane owns one float4 chunk. No atomics.
template <int F, bool TANH>
__global__ __launch_bounds__(256) void k_agg_csr(const int* __restrict__ row_start,
                                                 const int* __restrict__ edge_src,
                                                 const float* __restrict__ edge_w,
                                                 const float* __restrict__ feat,
                                                 float* __restrict__ out, int M) {
    constexpr int LPN = F / 4;
    constexpr int NPB = 256 / LPN;
    int n = blockIdx.x * NPB + threadIdx.x / LPN;
    int c = threadIdx.x % LPN;
    if (n >= M) return;
    int beg = row_start[n], end = row_start[n + 1];
    float4 acc = *(const float4*)(out + (long)n * F + c * 4);  // bias + self-loop term
    for (int j = beg; j < end; j++) {
        int s   = edge_src[j];   // same addr across the LPN lanes -> broadcast
        float w = edge_w[j];
        float4 v = *(const float4*)(feat + (long)s * F + c * 4);
        acc.x += v.x * w; acc.y += v.y * w; acc.z += v.z * w; acc.w += v.w * w;
    }
    if (TANH) {
        acc.x = tanhf(acc.x); acc.y = tanhf(acc.y);
        acc.z = tanhf(acc.z); acc.w = tanhf(acc.w);
    }
    *(float4*)(out + (long)n * F + c * 4) = acc;
}

extern "C" void kernel_launch(void* const* d_in, const int* in_sizes, int n_in,
                              void* d_out, int out_size, void* d_ws, size_t ws_size,
                              hipStream_t stream) {
    const float* x  = (const float*)d_in[0];
    const int*   ei = (const int*)d_in[1];
    const float* W1 = (const float*)d_in[2];
    const float* b1 = (const float*)d_in[3];
    const float* W2 = (const float*)d_in[4];
    const float* b2 = (const float*)d_in[5];
    float* out = (float*)d_out;

    const int M = in_sizes[0] / INDIM;   // 50000
    const int E = in_sizes[1] / 2;       // 800000
    const int* srcp = ei;
    const int* dstp = ei + E;

    const int Mp = (M + 63) & ~63;
    const int NB = (M + 255) / 256;      // 196 <= 256

    // workspace layout
    float* dinv     = (float*)d_ws;
    int*   counts   = (int*)(dinv + Mp);
    int*   cursor   = counts + Mp;
    int*   row_start= cursor + Mp;       // needs M+1 <= Mp
    int*   bsum     = row_start + Mp;
    int*   edge_src = bsum + 256;
    float* edge_w   = (float*)(edge_src + E);
    float* xw       = edge_w + E;        // M*HID
    float* h        = xw + (long)M * HID;
    float* hw       = xw;                // alias: xw dead after agg1

    // ---- CSR build + dinv ----
    k_zero2<<<(M + 255) / 256, 256, 0, stream>>>(counts, cursor, M);
    k_count<<<(E + 255) / 256, 256, 0, stream>>>(dstp, counts, E);
    k_breduce<<<NB, 256, 0, stream>>>(counts, bsum, M);
    k_bscan<<<1, 256, 0, stream>>>(bsum, NB);
    k_scan_final<<<NB, 256, 0, stream>>>(counts, bsum, row_start, dinv, M);
    k_fill<<<(E + 255) / 256, 256, 0, stream>>>(srcp, dstp, row_start, cursor, dinv, edge_src, edge_w, E);

    // ---- layer 1: xw = x@W1 ; h = b1 + xw*dinv^2 ; h += edges ; tanh ----
    k_gemm_init<128, 128, INDIM><<<(M + 127) / 128, 256, 0, stream>>>(x, W1, b1, dinv, xw, h, M);
    k_agg_csr<HID, true><<<(M + 7) / 8, 256, 0, stream>>>(row_start, edge_src, edge_w, xw, h, M);

    // ---- layer 2: hw = h@W2 ; out = b2 + hw*dinv^2 ; out += edges ----
    k_gemm_init<256, 64, HID><<<(M + 255) / 256, 256, 0, stream>>>(h, W2, b2, dinv, hw, out, M);
    k_agg_csr<OUTD, false><<<(M + 15) / 16, 256, 0, stream>>>(row_start, edge_src, edge_w, hw, out, M);
}

// Round 3
// 324.028 us; speedup vs baseline: 6.9964x; 1.2231x over previous
//
#include <hip/hip_runtime.h>

#define INDIM 256
#define HID 128
#define OUTD 64

typedef _Float16 f16x8 __attribute__((ext_vector_type(8)));
typedef float    f32x4 __attribute__((ext_vector_type(4)));

// =============== CSR build ===============

__global__ __launch_bounds__(256) void k_zero2(int* __restrict__ a, int* __restrict__ b, int n) {
    int i = blockIdx.x * 256 + threadIdx.x;
    if (i < n) { a[i] = 0; b[i] = 0; }
}

__global__ __launch_bounds__(256) void k_count(const int* __restrict__ dst, int* __restrict__ counts, int E) {
    int e = blockIdx.x * 256 + threadIdx.x;
    if (e < E) atomicAdd(&counts[dst[e]], 1);
}

__global__ __launch_bounds__(256) void k_breduce(const int* __restrict__ counts, int* __restrict__ bsum, int M) {
    __shared__ int s[256];
    int tid = threadIdx.x;
    int i = blockIdx.x * 256 + tid;
    s[tid] = (i < M) ? counts[i] : 0;
    __syncthreads();
#pragma unroll
    for (int off = 128; off > 0; off >>= 1) {
        if (tid < off) s[tid] += s[tid + off];
        __syncthreads();
    }
    if (tid == 0) bsum[blockIdx.x] = s[0];
}

__global__ __launch_bounds__(256) void k_bscan(int* __restrict__ bsum, int NB) {
    __shared__ int s[256];
    int tid = threadIdx.x;
    int v = (tid < NB) ? bsum[tid] : 0;
    s[tid] = v;
    __syncthreads();
#pragma unroll
    for (int off = 1; off < 256; off <<= 1) {
        int t = (tid >= off) ? s[tid - off] : 0;
        __syncthreads();
        s[tid] += t;
        __syncthreads();
    }
    if (tid < NB) bsum[tid] = s[tid] - v;  // exclusive
}

__global__ __launch_bounds__(256) void k_scan_final(const int* __restrict__ counts, const int* __restrict__ bsum,
                                                    int* __restrict__ row_start, float* __restrict__ dinv, int M) {
    __shared__ int s[256];
    int tid = threadIdx.x;
    int i = blockIdx.x * 256 + tid;
    int v = (i < M) ? counts[i] : 0;
    s[tid] = v;
    __syncthreads();
#pragma unroll
    for (int off = 1; off < 256; off <<= 1) {
        int t = (tid >= off) ? s[tid - off] : 0;
        __syncthreads();
        s[tid] += t;
        __syncthreads();
    }
    if (i < M) {
        int excl = bsum[blockIdx.x] + s[tid] - v;
        row_start[i] = excl;
        dinv[i] = rsqrtf(1.0f + (float)v);
        if (i == M - 1) row_start[M] = excl + v;
    }
}

__global__ __launch_bounds__(256) void k_fill(const int* __restrict__ src, const int* __restrict__ dst,
                                              const int* __restrict__ row_start, int* __restrict__ cursor,
                                              const float* __restrict__ dinv,
                                              int* __restrict__ edge_src, float* __restrict__ edge_w, int E) {
    int e = blockIdx.x * 256 + threadIdx.x;
    if (e >= E) return;
    int s = src[e], d = dst[e];
    int pos = row_start[d] + atomicAdd(&cursor[d], 1);
    edge_src[pos] = s;
    edge_w[pos] = dinv[s] * dinv[d];
}

// =============== weight prep: W[K][N] fp32 -> Wt[N][K] fp16 ===============
__global__ __launch_bounds__(256) void k_prepw(const float* __restrict__ W, _Float16* __restrict__ Wt,
                                               int K, int N) {
    int id = blockIdx.x * 256 + threadIdx.x;
    if (id < N * K) {
        int n = id / K, k = id % K;
        Wt[id] = (_Float16)W[k * N + n];
    }
}

// =============== MFMA fp16 GEMM + epilogue ===============
// X[M][K] fp32, Wt[BN][K] fp16 (pre-transposed). Computes C = X@W (fp32 acc),
// writes XW = C and INIT = bias + C * dinv[row]^2.
// BM=64, 256 threads = 4 waves; wave w owns rows [w*16, w*16+16), all BN cols.
template <int BN, int K>
__global__ __launch_bounds__(256) void k_gemm_mfma(
    const float* __restrict__ X, const _Float16* __restrict__ Wt,
    const float* __restrict__ bias, const float* __restrict__ dinv,
    float* __restrict__ XW, float* __restrict__ INIT, int M)
{
    constexpr int BM = 64;
    constexpr int BK = 32;
    constexpr int NT = BN / 16;   // n-tiles per wave
    constexpr int LDK = BK + 8;   // 40 halfs = 80 B row stride: 16B-aligned, 2-way-bank-free

    __shared__ __align__(16) _Float16 As[BM][LDK];
    __shared__ __align__(16) _Float16 Bs[BN][LDK];

    const int tid  = threadIdx.x;
    const int wave = tid >> 6;
    const int lane = tid & 63;
    const int m    = lane & 15;   // fragment row / col index
    const int q    = lane >> 4;   // quad
    const int rb   = blockIdx.x * BM;

    f32x4 acc[NT];
#pragma unroll
    for (int t = 0; t < NT; t++) acc[t] = (f32x4){0.f, 0.f, 0.f, 0.f};

    for (int kt = 0; kt < K; kt += BK) {
        if (kt) __syncthreads();
        // ---- stage A: BM x BK fp32 -> fp16, 8 float4-chunks per row ----
#pragma unroll
        for (int i = 0; i < BM * 8 / 256; i++) {
            int ch  = tid + i * 256;
            int row = ch >> 3;
            int c4  = ch & 7;
            int gr  = rb + row;
            float4 v = make_float4(0.f, 0.f, 0.f, 0.f);
            if (gr < M) v = *(const float4*)(X + (long)gr * K + kt + c4 * 4);
            _Float16* p = &As[row][c4 * 4];
            p[0] = (_Float16)v.x; p[1] = (_Float16)v.y;
            p[2] = (_Float16)v.z; p[3] = (_Float16)v.w;
        }
        // ---- stage B: BN rows of Wt, k-slice [kt, kt+32), ushort4 chunks ----
#pragma unroll
        for (int i = 0; i < BN * 8 / 256; i++) {
            int ch = tid + i * 256;
            int n  = ch >> 3;
            int c4 = ch & 7;
            *(ushort4*)(&Bs[n][c4 * 4]) =
                *(const ushort4*)(Wt + (long)n * K + kt + c4 * 4);
        }
        __syncthreads();

        // ---- fragments + MFMA ----
        f16x8 af = *(const f16x8*)(&As[wave * 16 + m][q * 8]);
#pragma unroll
        for (int t = 0; t < NT; t++) {
            f16x8 bf = *(const f16x8*)(&Bs[t * 16 + m][q * 8]);
            acc[t] = __builtin_amdgcn_mfma_f32_16x16x32_f16(af, bf, acc[t], 0, 0, 0);
        }
    }

    // ---- epilogue: C/D layout col=lane&15, row=quad*4+reg ----
    float bias_c[NT];
#pragma unroll
    for (int t = 0; t < NT; t++) bias_c[t] = bias[t * 16 + m];
    int row0 = rb + wave * 16 + q * 4;
    float di2[4];
#pragma unroll
    for (int r = 0; r < 4; r++) {
        int row = row0 + r;
        float di = (row < M) ? dinv[row] : 0.f;
        di2[r] = di * di;
    }
#pragma unroll
    for (int r = 0; r < 4; r++) {
        int row = row0 + r;
        if (row < M) {
#pragma unroll
            for (int t = 0; t < NT; t++) {
                int col = t * 16 + m;
                long idx = (long)row * BN + col;
                float c = acc[t][r];
                XW[idx] = c;
                INIT[idx] = bias_c[t] + c * di2[r];
            }
        }
    }
}

// =============== CSR gather-aggregation (no atomics) ===============
template <int F, bool TANH>
__global__ __launch_bounds__(256) void k_agg_csr(const int* __restrict__ row_start,
                                                 const int* __restrict__ edge_src,
                                                 const float* __restrict__ edge_w,
                                                 const float* __restrict__ feat,
                                                 float* __restrict__ out, int M) {
    constexpr int LPN = F / 4;
    constexpr int NPB = 256 / LPN;
    int n = blockIdx.x * NPB + threadIdx.x / LPN;
    int c = threadIdx.x % LPN;
    if (n >= M) return;
    int beg = row_start[n], end = row_start[n + 1];
    float4 acc = *(const float4*)(out + (long)n * F + c * 4);  // bias + self-loop term
    for (int j = beg; j < end; j++) {
        int s   = edge_src[j];
        float w = edge_w[j];
        float4 v = *(const float4*)(feat + (long)s * F + c * 4);
        acc.x += v.x * w; acc.y += v.y * w; acc.z += v.z * w; acc.w += v.w * w;
    }
    if (TANH) {
        acc.x = tanhf(acc.x); acc.y = tanhf(acc.y);
        acc.z = tanhf(acc.z); acc.w = tanhf(acc.w);
    }
    *(float4*)(out + (long)n * F + c * 4) = acc;
}

extern "C" void kernel_launch(void* const* d_in, const int* in_sizes, int n_in,
                              void* d_out, int out_size, void* d_ws, size_t ws_size,
                              hipStream_t stream) {
    const float* x  = (const float*)d_in[0];
    const int*   ei = (const int*)d_in[1];
    const float* W1 = (const float*)d_in[2];
    const float* b1 = (const float*)d_in[3];
    const float* W2 = (const float*)d_in[4];
    const float* b2 = (const float*)d_in[5];
    float* out = (float*)d_out;

    const int M = in_sizes[0] / INDIM;   // 50000
    const int E = in_sizes[1] / 2;       // 800000
    const int* srcp = ei;
    const int* dstp = ei + E;

    const int Mp = (M + 63) & ~63;
    const int NB = (M + 255) / 256;

    // workspace layout
    float*     dinv      = (float*)d_ws;
    int*       counts    = (int*)(dinv + Mp);
    int*       cursor    = counts + Mp;
    int*       row_start = cursor + Mp;      // M+1 <= Mp
    int*       bsum      = row_start + Mp;
    _Float16*  W1t       = (_Float16*)(bsum + 256);        // [HID][INDIM]
    _Float16*  W2t       = W1t + HID * INDIM;              // [OUTD][HID]
    int*       edge_src  = (int*)(W2t + OUTD * HID);
    float*     edge_w    = (float*)(edge_src + E);
    float*     xw        = edge_w + E;       // M*HID
    float*     h         = xw + (long)M * HID;
    float*     hw        = xw;               // alias: xw dead after agg1

    // ---- weight prep (fp32 -> fp16, transposed) ----
    k_prepw<<<(HID * INDIM + 255) / 256, 256, 0, stream>>>(W1, W1t, INDIM, HID);
    k_prepw<<<(OUTD * HID + 255) / 256, 256, 0, stream>>>(W2, W2t, HID, OUTD);

    // ---- CSR build + dinv ----
    k_zero2<<<(M + 255) / 256, 256, 0, stream>>>(counts, cursor, M);
    k_count<<<(E + 255) / 256, 256, 0, stream>>>(dstp, counts, E);
    k_breduce<<<NB, 256, 0, stream>>>(counts, bsum, M);
    k_bscan<<<1, 256, 0, stream>>>(bsum, NB);
    k_scan_final<<<NB, 256, 0, stream>>>(counts, bsum, row_start, dinv, M);
    k_fill<<<(E + 255) / 256, 256, 0, stream>>>(srcp, dstp, row_start, cursor, dinv, edge_src, edge_w, E);

    // ---- layer 1: xw = x@W1 ; h = b1 + xw*dinv^2 ; h += edges ; tanh ----
    k_gemm_mfma<HID, INDIM><<<(M + 63) / 64, 256, 0, stream>>>(x, W1t, b1, dinv, xw, h, M);
    k_agg_csr<HID, true><<<(M + 7) / 8, 256, 0, stream>>>(row_start, edge_src, edge_w, xw, h, M);

    // ---- layer 2: hw = h@W2 ; out = b2 + hw*dinv^2 ; out += edges ----
    k_gemm_mfma<OUTD, HID><<<(M + 63) / 64, 256, 0, stream>>>(h, W2t, b2, dinv, hw, out, M);
    k_agg_csr<OUTD, false><<<(M + 15) / 16, 256, 0, stream>>>(row_start, edge_src, edge_w, hw, out, M);
}

// Round 4
// 271.870 us; speedup vs baseline: 8.3387x; 1.1918x over previous
//
#include <hip/hip_runtime.h>

#define INDIM 256
#define HID 128
#define OUTD 64

typedef _Float16 f16x8 __attribute__((ext_vector_type(8)));
typedef float    f32x4 __attribute__((ext_vector_type(4)));

// =============== CSR build ===============

__global__ __launch_bounds__(256) void k_zero2(int* __restrict__ a, int* __restrict__ b, int n) {
    int i = blockIdx.x * 256 + threadIdx.x;
    if (i < n) { a[i] = 0; b[i] = 0; }
}

__global__ __launch_bounds__(256) void k_count(const int* __restrict__ dst, int* __restrict__ counts, int E) {
    int e = blockIdx.x * 256 + threadIdx.x;
    if (e < E) atomicAdd(&counts[dst[e]], 1);
}

__global__ __launch_bounds__(256) void k_breduce(const int* __restrict__ counts, int* __restrict__ bsum, int M) {
    __shared__ int s[256];
    int tid = threadIdx.x;
    int i = blockIdx.x * 256 + tid;
    s[tid] = (i < M) ? counts[i] : 0;
    __syncthreads();
#pragma unroll
    for (int off = 128; off > 0; off >>= 1) {
        if (tid < off) s[tid] += s[tid + off];
        __syncthreads();
    }
    if (tid == 0) bsum[blockIdx.x] = s[0];
}

__global__ __launch_bounds__(256) void k_bscan(int* __restrict__ bsum, int NB) {
    __shared__ int s[256];
    int tid = threadIdx.x;
    int v = (tid < NB) ? bsum[tid] : 0;
    s[tid] = v;
    __syncthreads();
#pragma unroll
    for (int off = 1; off < 256; off <<= 1) {
        int t = (tid >= off) ? s[tid - off] : 0;
        __syncthreads();
        s[tid] += t;
        __syncthreads();
    }
    if (tid < NB) bsum[tid] = s[tid] - v;  // exclusive
}

__global__ __launch_bounds__(256) void k_scan_final(const int* __restrict__ counts, const int* __restrict__ bsum,
                                                    int* __restrict__ row_start, float* __restrict__ dinv, int M) {
    __shared__ int s[256];
    int tid = threadIdx.x;
    int i = blockIdx.x * 256 + tid;
    int v = (i < M) ? counts[i] : 0;
    s[tid] = v;
    __syncthreads();
#pragma unroll
    for (int off = 1; off < 256; off <<= 1) {
        int t = (tid >= off) ? s[tid - off] : 0;
        __syncthreads();
        s[tid] += t;
        __syncthreads();
    }
    if (i < M) {
        int excl = bsum[blockIdx.x] + s[tid] - v;
        row_start[i] = excl;
        dinv[i] = rsqrtf(1.0f + (float)v);
        if (i == M - 1) row_start[M] = excl + v;
    }
}

// edges[pos] = {src, bits(dinv[src]*dinv[dst])}
__global__ __launch_bounds__(256) void k_fill(const int* __restrict__ src, const int* __restrict__ dst,
                                              const int* __restrict__ row_start, int* __restrict__ cursor,
                                              const float* __restrict__ dinv,
                                              int2* __restrict__ edges, int E) {
    int e = blockIdx.x * 256 + threadIdx.x;
    if (e >= E) return;
    int s = src[e], d = dst[e];
    int pos = row_start[d] + atomicAdd(&cursor[d], 1);
    edges[pos] = make_int2(s, __float_as_int(dinv[s] * dinv[d]));
}

// =============== weight prep: W[K][N] fp32 -> Wt[N][K] fp16 ===============
__global__ __launch_bounds__(256) void k_prepw(const float* __restrict__ W, _Float16* __restrict__ Wt,
                                               int K, int N) {
    int id = blockIdx.x * 256 + threadIdx.x;
    if (id < N * K) {
        int n = id / K, k = id % K;
        Wt[id] = (_Float16)W[k * N + n];
    }
}

// =============== MFMA fp16 GEMM, fp16 output ===============
// X[M][K] (fp32 or fp16), Wt[BN][K] fp16 (pre-transposed). XW16 = fp16(X@W).
// BM=64, 4 waves; wave w owns rows [w*16, w*16+16), all BN cols.
template <int BN, int K, typename AT>
__global__ __launch_bounds__(256) void k_gemm_mfma(
    const AT* __restrict__ X, const _Float16* __restrict__ Wt,
    _Float16* __restrict__ XW16, int M)
{
    constexpr int BM = 64;
    constexpr int BK = 32;
    constexpr int NT = BN / 16;
    constexpr int LDK = BK + 8;   // 40 halfs = 80 B stride, 16B-aligned

    __shared__ __align__(16) _Float16 As[BM][LDK];
    __shared__ __align__(16) _Float16 Bs[BN][LDK];

    const int tid  = threadIdx.x;
    const int wave = tid >> 6;
    const int lane = tid & 63;
    const int m    = lane & 15;
    const int q    = lane >> 4;
    const int rb   = blockIdx.x * BM;

    f32x4 acc[NT];
#pragma unroll
    for (int t = 0; t < NT; t++) acc[t] = (f32x4){0.f, 0.f, 0.f, 0.f};

    for (int kt = 0; kt < K; kt += BK) {
        if (kt) __syncthreads();
        // ---- stage A ----
        if constexpr (sizeof(AT) == 4) {
            // fp32 -> fp16 convert: BM rows x 8 float4-chunks = 512 chunks
#pragma unroll
            for (int i = 0; i < BM * 8 / 256; i++) {
                int ch  = tid + i * 256;
                int row = ch >> 3;
                int c4  = ch & 7;
                int gr  = rb + row;
                float4 v = make_float4(0.f, 0.f, 0.f, 0.f);
                if (gr < M) v = *(const float4*)((const float*)X + (long)gr * K + kt + c4 * 4);
                _Float16* p = &As[row][c4 * 4];
                p[0] = (_Float16)v.x; p[1] = (_Float16)v.y;
                p[2] = (_Float16)v.z; p[3] = (_Float16)v.w;
            }
        } else {
            // fp16 direct copy: BM rows x 4 chunks-of-8-halfs = 256 chunks
            int row = tid >> 2;
            int c8  = tid & 3;
            int gr  = rb + row;
            uint4 v = make_uint4(0u, 0u, 0u, 0u);
            if (gr < M) v = *(const uint4*)((const _Float16*)X + (long)gr * K + kt + c8 * 8);
            *(uint4*)(&As[row][c8 * 8]) = v;
        }
        // ---- stage B: BN rows x 8 ushort4-chunks ----
#pragma unroll
        for (int i = 0; i < BN * 8 / 256; i++) {
            int ch = tid + i * 256;
            int n  = ch >> 3;
            int c4 = ch & 7;
            *(ushort4*)(&Bs[n][c4 * 4]) =
                *(const ushort4*)(Wt + (long)n * K + kt + c4 * 4);
        }
        __syncthreads();

        f16x8 af = *(const f16x8*)(&As[wave * 16 + m][q * 8]);
#pragma unroll
        for (int t = 0; t < NT; t++) {
            f16x8 bf = *(const f16x8*)(&Bs[t * 16 + m][q * 8]);
            acc[t] = __builtin_amdgcn_mfma_f32_16x16x32_f16(af, bf, acc[t], 0, 0, 0);
        }
    }

    // ---- epilogue: C/D layout col=lane&15, row=quad*4+reg; store fp16 ----
    int row0 = rb + wave * 16 + q * 4;
#pragma unroll
    for (int r = 0; r < 4; r++) {
        int row = row0 + r;
        if (row < M) {
#pragma unroll
            for (int t = 0; t < NT; t++) {
                XW16[(long)row * BN + t * 16 + m] = (_Float16)acc[t][r];
            }
        }
    }
}

// =============== CSR gather-aggregation (fp16 table, no atomics) ===============
// out[n] = act(bias + feat[n]*dinv[n]^2 + sum_e feat[edges[e].src]*w_e)
template <int F, bool TANH, typename OutT>
__global__ __launch_bounds__(256) void k_agg_csr(const int* __restrict__ row_start,
                                                 const int2* __restrict__ edges,
                                                 const _Float16* __restrict__ feat,
                                                 const float* __restrict__ bias,
                                                 const float* __restrict__ dinv,
                                                 OutT* __restrict__ out, int M) {
    constexpr int LPN = F / 8;          // lanes per node, 8 halfs (16B) each
    constexpr int NPB = 256 / LPN;
    int n = blockIdx.x * NPB + threadIdx.x / LPN;
    int c = threadIdx.x % LPN;
    if (n >= M) return;
    int beg = row_start[n], end = row_start[n + 1];
    float di  = dinv[n];
    float di2 = di * di;

    f16x8 self = *(const f16x8*)(feat + (long)n * F + c * 8);
    float acc[8];
#pragma unroll
    for (int k = 0; k < 8; k++) acc[k] = bias[c * 8 + k] + (float)self[k] * di2;

    for (int j = beg; j < end; j++) {
        int2 e  = edges[j];              // broadcast across LPN lanes
        float w = __int_as_float(e.y);
        f16x8 v = *(const f16x8*)(feat + (long)e.x * F + c * 8);
#pragma unroll
        for (int k = 0; k < 8; k++) acc[k] += (float)v[k] * w;
    }
    if (TANH) {
#pragma unroll
        for (int k = 0; k < 8; k++) acc[k] = tanhf(acc[k]);
    }
    if constexpr (sizeof(OutT) == 2) {
        f16x8 o;
#pragma unroll
        for (int k = 0; k < 8; k++) o[k] = (_Float16)acc[k];
        *(f16x8*)((_Float16*)out + (long)n * F + c * 8) = o;
    } else {
        float* p = (float*)out + (long)n * F + c * 8;
        *(float4*)(p)     = make_float4(acc[0], acc[1], acc[2], acc[3]);
        *(float4*)(p + 4) = make_float4(acc[4], acc[5], acc[6], acc[7]);
    }
}

extern "C" void kernel_launch(void* const* d_in, const int* in_sizes, int n_in,
                              void* d_out, int out_size, void* d_ws, size_t ws_size,
                              hipStream_t stream) {
    const float* x  = (const float*)d_in[0];
    const int*   ei = (const int*)d_in[1];
    const float* W1 = (const float*)d_in[2];
    const float* b1 = (const float*)d_in[3];
    const float* W2 = (const float*)d_in[4];
    const float* b2 = (const float*)d_in[5];
    float* out = (float*)d_out;

    const int M = in_sizes[0] / INDIM;   // 50000
    const int E = in_sizes[1] / 2;       // 800000
    const int* srcp = ei;
    const int* dstp = ei + E;

    const int Mp = (M + 63) & ~63;
    const int NB = (M + 255) / 256;

    // workspace layout (all 16B-aligned offsets)
    float*     dinv      = (float*)d_ws;
    int*       counts    = (int*)(dinv + Mp);
    int*       cursor    = counts + Mp;
    int*       row_start = cursor + Mp;          // M+1 <= Mp
    int*       bsum      = row_start + Mp;
    _Float16*  W1t       = (_Float16*)(bsum + 256);   // [HID][INDIM]
    _Float16*  W2t       = W1t + HID * INDIM;         // [OUTD][HID]
    int2*      edges     = (int2*)(W2t + OUTD * HID); // [E]
    _Float16*  xw16      = (_Float16*)(edges + E);    // [M][HID]
    _Float16*  h16       = xw16 + (long)M * HID;      // [M][HID]
    _Float16*  hw16      = xw16;                      // alias: xw dead after agg1

    // ---- weight prep ----
    k_prepw<<<(HID * INDIM + 255) / 256, 256, 0, stream>>>(W1, W1t, INDIM, HID);
    k_prepw<<<(OUTD * HID + 255) / 256, 256, 0, stream>>>(W2, W2t, HID, OUTD);

    // ---- CSR build + dinv ----
    k_zero2<<<(M + 255) / 256, 256, 0, stream>>>(counts, cursor, M);
    k_count<<<(E + 255) / 256, 256, 0, stream>>>(dstp, counts, E);
    k_breduce<<<NB, 256, 0, stream>>>(counts, bsum, M);
    k_bscan<<<1, 256, 0, stream>>>(bsum, NB);
    k_scan_final<<<NB, 256, 0, stream>>>(counts, bsum, row_start, dinv, M);
    k_fill<<<(E + 255) / 256, 256, 0, stream>>>(srcp, dstp, row_start, cursor, dinv, edges, E);

    // ---- layer 1: xw16 = fp16(x@W1) ; h16 = tanh(b1 + self + edges) ----
    k_gemm_mfma<HID, INDIM, float><<<(M + 63) / 64, 256, 0, stream>>>(x, W1t, xw16, M);
    k_agg_csr<HID, true, _Float16><<<(M + 15) / 16, 256, 0, stream>>>(row_start, edges, xw16, b1, dinv, h16, M);

    // ---- layer 2: hw16 = fp16(h@W2) ; out = b2 + self + edges ----
    k_gemm_mfma<OUTD, HID, _Float16><<<(M + 63) / 64, 256, 0, stream>>>(h16, W2t, hw16, M);
    k_agg_csr<OUTD, false, float><<<(M + 31) / 32, 256, 0, stream>>>(row_start, edges, hw16, b2, dinv, out, M);
}

// Round 5
// 254.615 us; speedup vs baseline: 8.9038x; 1.0678x over previous
//
#include <hip/hip_runtime.h>

#define INDIM 256
#define HID 128
#define OUTD 64

typedef _Float16 f16x8 __attribute__((ext_vector_type(8)));
typedef float    f32x4 __attribute__((ext_vector_type(4)));

// =============== fused setup: weight transpose/convert + zero counts/cursor ===============
// W1[INDIM][HID] -> W1t[HID][INDIM] fp16 ; W2[HID][OUTD] -> W2t[OUTD][HID] fp16
__global__ __launch_bounds__(256) void k_setup(const float* __restrict__ W1, const float* __restrict__ W2,
                                               _Float16* __restrict__ W1t, _Float16* __restrict__ W2t,
                                               int* __restrict__ counts, int* __restrict__ cursor, int M) {
    constexpr int NW1 = HID * INDIM;   // 32768
    constexpr int NW2 = OUTD * HID;    // 8192
    int id = blockIdx.x * 256 + threadIdx.x;
    if (id < NW1) {
        int n = id / INDIM, k = id % INDIM;
        W1t[id] = (_Float16)W1[k * HID + n];
    } else if (id < NW1 + NW2) {
        int j = id - NW1;
        int n = j / HID, k = j % HID;
        W2t[j] = (_Float16)W2[k * OUTD + n];
    } else {
        int i = id - NW1 - NW2;
        if (i < M) { counts[i] = 0; cursor[i] = 0; }
    }
}

// =============== CSR build ===============

__global__ __launch_bounds__(256) void k_count(const int* __restrict__ dst, int* __restrict__ counts, int E) {
    int e = blockIdx.x * 256 + threadIdx.x;
    if (e < E) atomicAdd(&counts[dst[e]], 1);
}

__global__ __launch_bounds__(256) void k_breduce(const int* __restrict__ counts, int* __restrict__ bsum, int M) {
    __shared__ int s[256];
    int tid = threadIdx.x;
    int i = blockIdx.x * 256 + tid;
    s[tid] = (i < M) ? counts[i] : 0;
    __syncthreads();
#pragma unroll
    for (int off = 128; off > 0; off >>= 1) {
        if (tid < off) s[tid] += s[tid + off];
        __syncthreads();
    }
    if (tid == 0) bsum[blockIdx.x] = s[0];
}

__global__ __launch_bounds__(256) void k_bscan(int* __restrict__ bsum, int NB) {
    __shared__ int s[256];
    int tid = threadIdx.x;
    int v = (tid < NB) ? bsum[tid] : 0;
    s[tid] = v;
    __syncthreads();
#pragma unroll
    for (int off = 1; off < 256; off <<= 1) {
        int t = (tid >= off) ? s[tid - off] : 0;
        __syncthreads();
        s[tid] += t;
        __syncthreads();
    }
    if (tid < NB) bsum[tid] = s[tid] - v;  // exclusive
}

__global__ __launch_bounds__(256) void k_scan_final(const int* __restrict__ counts, const int* __restrict__ bsum,
                                                    int* __restrict__ row_start, float* __restrict__ dinv, int M) {
    __shared__ int s[256];
    int tid = threadIdx.x;
    int i = blockIdx.x * 256 + tid;
    int v = (i < M) ? counts[i] : 0;
    s[tid] = v;
    __syncthreads();
#pragma unroll
    for (int off = 1; off < 256; off <<= 1) {
        int t = (tid >= off) ? s[tid - off] : 0;
        __syncthreads();
        s[tid] += t;
        __syncthreads();
    }
    if (i < M) {
        int excl = bsum[blockIdx.x] + s[tid] - v;
        row_start[i] = excl;
        dinv[i] = rsqrtf(1.0f + (float)v);
        if (i == M - 1) row_start[M] = excl + v;
    }
}

// 4-byte edge records: just src (weights folded into pre-scaled features)
__global__ __launch_bounds__(256) void k_fill(const int* __restrict__ src, const int* __restrict__ dst,
                                              const int* __restrict__ row_start, int* __restrict__ cursor,
                                              int* __restrict__ edge_src, int E) {
    int e = blockIdx.x * 256 + threadIdx.x;
    if (e >= E) return;
    int d = dst[e];
    int pos = row_start[d] + atomicAdd(&cursor[d], 1);
    edge_src[pos] = src[e];
}

// =============== MFMA fp16 GEMM, pre-scaled fp16 output ===============
// X[M][K] (fp32 or fp16), Wt[BN][K] fp16. XW16[row] = fp16((X@W)[row] * dinv[row]).
template <int BN, int K, typename AT>
__global__ __launch_bounds__(256) void k_gemm_mfma(
    const AT* __restrict__ X, const _Float16* __restrict__ Wt,
    const float* __restrict__ dinv, _Float16* __restrict__ XW16, int M)
{
    constexpr int BM = 64;
    constexpr int BK = 32;
    constexpr int NT = BN / 16;
    constexpr int LDK = BK + 8;   // 40 halfs = 80 B stride, 16B-aligned

    __shared__ __align__(16) _Float16 As[BM][LDK];
    __shared__ __align__(16) _Float16 Bs[BN][LDK];

    const int tid  = threadIdx.x;
    const int wave = tid >> 6;
    const int lane = tid & 63;
    const int m    = lane & 15;
    const int q    = lane >> 4;
    const int rb   = blockIdx.x * BM;

    f32x4 acc[NT];
#pragma unroll
    for (int t = 0; t < NT; t++) acc[t] = (f32x4){0.f, 0.f, 0.f, 0.f};

    for (int kt = 0; kt < K; kt += BK) {
        if (kt) __syncthreads();
        if constexpr (sizeof(AT) == 4) {
#pragma unroll
            for (int i = 0; i < BM * 8 / 256; i++) {
                int ch  = tid + i * 256;
                int row = ch >> 3;
                int c4  = ch & 7;
                int gr  = rb + row;
                float4 v = make_float4(0.f, 0.f, 0.f, 0.f);
                if (gr < M) v = *(const float4*)((const float*)X + (long)gr * K + kt + c4 * 4);
                _Float16* p = &As[row][c4 * 4];
                p[0] = (_Float16)v.x; p[1] = (_Float16)v.y;
                p[2] = (_Float16)v.z; p[3] = (_Float16)v.w;
            }
        } else {
            int row = tid >> 2;
            int c8  = tid & 3;
            int gr  = rb + row;
            uint4 v = make_uint4(0u, 0u, 0u, 0u);
            if (gr < M) v = *(const uint4*)((const _Float16*)X + (long)gr * K + kt + c8 * 8);
            *(uint4*)(&As[row][c8 * 8]) = v;
        }
#pragma unroll
        for (int i = 0; i < BN * 8 / 256; i++) {
            int ch = tid + i * 256;
            int n  = ch >> 3;
            int c4 = ch & 7;
            *(ushort4*)(&Bs[n][c4 * 4]) =
                *(const ushort4*)(Wt + (long)n * K + kt + c4 * 4);
        }
        __syncthreads();

        f16x8 af = *(const f16x8*)(&As[wave * 16 + m][q * 8]);
#pragma unroll
        for (int t = 0; t < NT; t++) {
            f16x8 bf = *(const f16x8*)(&Bs[t * 16 + m][q * 8]);
            acc[t] = __builtin_amdgcn_mfma_f32_16x16x32_f16(af, bf, acc[t], 0, 0, 0);
        }
    }

    // epilogue: C/D layout col=lane&15, row=quad*4+reg; scale by dinv[row], store fp16
    int row0 = rb + wave * 16 + q * 4;
#pragma unroll
    for (int r = 0; r < 4; r++) {
        int row = row0 + r;
        if (row < M) {
            float di = dinv[row];
#pragma unroll
            for (int t = 0; t < NT; t++) {
                XW16[(long)row * BN + t * 16 + m] = (_Float16)(acc[t][r] * di);
            }
        }
    }
}

// =============== CSR gather-aggregation (pre-scaled fp16 table) ===============
// out[n] = act(bias + dinv[n] * (feat[n] + sum_{e in(n)} feat[src_e]))
template <int F, bool TANH, typename OutT>
__global__ __launch_bounds__(256) void k_agg_csr(const int* __restrict__ row_start,
                                                 const int* __restrict__ edge_src,
                                                 const _Float16* __restrict__ feat,
                                                 const float* __restrict__ bias,
                                                 const float* __restrict__ dinv,
                                                 OutT* __restrict__ out, int M) {
    constexpr int LPN = F / 8;          // lanes per node, 8 halfs (16B) each
    constexpr int NPB = 256 / LPN;
    int n = blockIdx.x * NPB + threadIdx.x / LPN;
    int c = threadIdx.x % LPN;
    if (n >= M) return;
    int beg = row_start[n], end = row_start[n + 1];

    f16x8 self = *(const f16x8*)(feat + (long)n * F + c * 8);
    float acc[8];
#pragma unroll
    for (int k = 0; k < 8; k++) acc[k] = (float)self[k];

    int j = beg;
    for (; j + 1 < end; j += 2) {
        int s0 = edge_src[j], s1 = edge_src[j + 1];
        f16x8 v0 = *(const f16x8*)(feat + (long)s0 * F + c * 8);
        f16x8 v1 = *(const f16x8*)(feat + (long)s1 * F + c * 8);
#pragma unroll
        for (int k = 0; k < 8; k++) acc[k] += (float)v0[k] + (float)v1[k];
    }
    if (j < end) {
        int s = edge_src[j];
        f16x8 v = *(const f16x8*)(feat + (long)s * F + c * 8);
#pragma unroll
        for (int k = 0; k < 8; k++) acc[k] += (float)v[k];
    }

    float di = dinv[n];
#pragma unroll
    for (int k = 0; k < 8; k++) acc[k] = bias[c * 8 + k] + di * acc[k];
    if (TANH) {
#pragma unroll
        for (int k = 0; k < 8; k++) acc[k] = tanhf(acc[k]);
    }
    if constexpr (sizeof(OutT) == 2) {
        f16x8 o;
#pragma unroll
        for (int k = 0; k < 8; k++) o[k] = (_Float16)acc[k];
        *(f16x8*)((_Float16*)out + (long)n * F + c * 8) = o;
    } else {
        float* p = (float*)out + (long)n * F + c * 8;
        *(float4*)(p)     = make_float4(acc[0], acc[1], acc[2], acc[3]);
        *(float4*)(p + 4) = make_float4(acc[4], acc[5], acc[6], acc[7]);
    }
}

extern "C" void kernel_launch(void* const* d_in, const int* in_sizes, int n_in,
                              void* d_out, int out_size, void* d_ws, size_t ws_size,
                              hipStream_t stream) {
    const float* x  = (const float*)d_in[0];
    const int*   ei = (const int*)d_in[1];
    const float* W1 = (const float*)d_in[2];
    const float* b1 = (const float*)d_in[3];
    const float* W2 = (const float*)d_in[4];
    const float* b2 = (const float*)d_in[5];
    float* out = (float*)d_out;

    const int M = in_sizes[0] / INDIM;   // 50000
    const int E = in_sizes[1] / 2;       // 800000
    const int* srcp = ei;
    const int* dstp = ei + E;

    const int Mp = (M + 63) & ~63;
    const int NB = (M + 255) / 256;

    // workspace layout (16B-aligned offsets)
    float*     dinv      = (float*)d_ws;
    int*       counts    = (int*)(dinv + Mp);
    int*       cursor    = counts + Mp;
    int*       row_start = cursor + Mp;            // M+1 <= Mp
    int*       bsum      = row_start + Mp;
    _Float16*  W1t       = (_Float16*)(bsum + 256);     // [HID][INDIM]
    _Float16*  W2t       = W1t + HID * INDIM;           // [OUTD][HID]
    int*       edge_src  = (int*)(W2t + OUTD * HID);    // [E]
    _Float16*  xw16      = (_Float16*)(edge_src + E);   // [M][HID] pre-scaled
    _Float16*  h16       = xw16 + (long)M * HID;        // [M][HID]
    _Float16*  hw16      = xw16;                        // alias: xw dead after agg1

    // ---- setup: weight prep + zero counts/cursor (one kernel) ----
    {
        int total = HID * INDIM + OUTD * HID + M;
        k_setup<<<(total + 255) / 256, 256, 0, stream>>>(W1, W2, W1t, W2t, counts, cursor, M);
    }

    // ---- CSR build + dinv ----
    k_count<<<(E + 255) / 256, 256, 0, stream>>>(dstp, counts, E);
    k_breduce<<<NB, 256, 0, stream>>>(counts, bsum, M);
    k_bscan<<<1, 256, 0, stream>>>(bsum, NB);
    k_scan_final<<<NB, 256, 0, stream>>>(counts, bsum, row_start, dinv, M);
    k_fill<<<(E + 255) / 256, 256, 0, stream>>>(srcp, dstp, row_start, cursor, edge_src, E);

    // ---- layer 1: xw16 = fp16((x@W1)*dinv) ; h16 = tanh(b1 + dinv*(self + edges)) ----
    k_gemm_mfma<HID, INDIM, float><<<(M + 63) / 64, 256, 0, stream>>>(x, W1t, dinv, xw16, M);
    k_agg_csr<HID, true, _Float16><<<(M + 15) / 16, 256, 0, stream>>>(row_start, edge_src, xw16, b1, dinv, h16, M);

    // ---- layer 2: hw16 = fp16((h@W2)*dinv) ; out = b2 + dinv*(self + edges) ----
    k_gemm_mfma<OUTD, HID, _Float16><<<(M + 63) / 64, 256, 0, stream>>>(h16, W2t, dinv, hw16, M);
    k_agg_csr<OUTD, false, float><<<(M + 31) / 32, 256, 0, stream>>>(row_start, edge_src, hw16, b2, dinv, out, M);
}

// Round 6
// 230.782 us; speedup vs baseline: 9.8233x; 1.1033x over previous
//
#include <hip/hip_runtime.h>

#define INDIM 256
#define HID 128
#define OUTD 64
#define BINSHIFT 8
#define MAXBIN 256   // supports M <= 65536

typedef _Float16 f16x8 __attribute__((ext_vector_type(8)));
typedef float    f32x4 __attribute__((ext_vector_type(4)));

// =============== setup: weight transpose/convert + zero bin counts ===============
__global__ __launch_bounds__(256) void k_setup(const float* __restrict__ W1, const float* __restrict__ W2,
                                               _Float16* __restrict__ W1t, _Float16* __restrict__ W2t,
                                               int* __restrict__ bin_counts) {
    constexpr int NW1 = HID * INDIM;   // 32768
    constexpr int NW2 = OUTD * HID;    // 8192
    int id = blockIdx.x * 256 + threadIdx.x;
    if (id < NW1) {
        int n = id / INDIM, k = id % INDIM;
        W1t[id] = (_Float16)W1[k * HID + n];
    } else if (id < NW1 + NW2) {
        int j = id - NW1;
        int n = j / HID, k = j % HID;
        W2t[j] = (_Float16)W2[k * OUTD + n];
    } else {
        int i = id - NW1 - NW2;
        if (i < MAXBIN) bin_counts[i] = 0;
    }
}

// =============== binned CSR build ===============
// Pass 1: per-wg LDS histogram of dst>>BINSHIFT, flushed with few global atomics.
__global__ __launch_bounds__(256) void k_hist(const int* __restrict__ dst, int* __restrict__ bin_counts, int E) {
    __shared__ int h[MAXBIN];
    int tid = threadIdx.x;
    h[tid] = 0;
    __syncthreads();
    int base = blockIdx.x * 2048;
#pragma unroll
    for (int i = 0; i < 8; i++) {
        int e = base + i * 256 + tid;
        if (e < E) atomicAdd(&h[dst[e] >> BINSHIFT], 1);
    }
    __syncthreads();
    int v = h[tid];
    if (v) atomicAdd(&bin_counts[tid], v);
}

// Pass 2: exclusive scan of bin counts -> bin_start, bin_cursor. One wg.
__global__ __launch_bounds__(256) void k_bscan(const int* __restrict__ bin_counts,
                                               int* __restrict__ bin_start, int* __restrict__ bin_cursor,
                                               int* __restrict__ row_start, int NBIN, int M, int E) {
    __shared__ int s[256];
    int tid = threadIdx.x;
    int v = (tid < NBIN) ? bin_counts[tid] : 0;
    s[tid] = v;
    __syncthreads();
#pragma unroll
    for (int off = 1; off < 256; off <<= 1) {
        int t = (tid >= off) ? s[tid - off] : 0;
        __syncthreads();
        s[tid] += t;
        __syncthreads();
    }
    if (tid < NBIN) {
        int excl = s[tid] - v;
        bin_start[tid] = excl;
        bin_cursor[tid] = excl;
    }
    if (tid == 0) {
        bin_start[NBIN] = E;
        row_start[M] = E;   // final CSR bound
    }
}

// Pass 3: scatter {src,dst} into bin-grouped array via per-wg run reservation.
// Writes advance each bin's frontier monotonically -> line-friendly.
__global__ __launch_bounds__(256) void k_binfill(const int* __restrict__ src, const int* __restrict__ dst,
                                                 int* __restrict__ bin_cursor, int2* __restrict__ binned, int E) {
    __shared__ int h[MAXBIN];
    __shared__ int rb[MAXBIN];
    int tid = threadIdx.x;
    h[tid] = 0;
    __syncthreads();
    int base = blockIdx.x * 2048;
    int es[8], ed[8], rk[8];
#pragma unroll
    for (int i = 0; i < 8; i++) {
        int e = base + i * 256 + tid;
        if (e < E) {
            es[i] = src[e];
            ed[i] = dst[e];
            rk[i] = atomicAdd(&h[ed[i] >> BINSHIFT], 1);
        } else {
            ed[i] = -1;
        }
    }
    __syncthreads();
    int c = h[tid];
    if (c) rb[tid] = atomicAdd(&bin_cursor[tid], c);
    __syncthreads();
#pragma unroll
    for (int i = 0; i < 8; i++) {
        if (ed[i] >= 0) {
            binned[rb[ed[i] >> BINSHIFT] + rk[i]] = make_int2(es[i], ed[i]);
        }
    }
}

// Pass 4: one wg per bin (256 nodes). Stream bin edges twice (L2-hot):
// node counts -> LDS scan -> row_start/dinv + CSR placement into a contiguous region.
__global__ __launch_bounds__(256) void k_csr(const int2* __restrict__ binned, const int* __restrict__ bin_start,
                                             int* __restrict__ row_start, float* __restrict__ dinv,
                                             int* __restrict__ edge_src, int M) {
    __shared__ int cnt[256];
    __shared__ int s[256];
    __shared__ int cur[256];
    int b = blockIdx.x, tid = threadIdx.x;
    int beg = bin_start[b], end = bin_start[b + 1];
    cnt[tid] = 0;
    __syncthreads();
    for (int i = beg + tid; i < end; i += 256) {
        atomicAdd(&cnt[binned[i].y & 255], 1);
    }
    __syncthreads();
    int c = cnt[tid];
    s[tid] = c;
    __syncthreads();
#pragma unroll
    for (int off = 1; off < 256; off <<= 1) {
        int t = (tid >= off) ? s[tid - off] : 0;
        __syncthreads();
        s[tid] += t;
        __syncthreads();
    }
    int start = beg + s[tid] - c;   // exclusive within bin
    int node = (b << BINSHIFT) + tid;
    if (node < M) {
        row_start[node] = start;
        dinv[node] = rsqrtf(1.0f + (float)c);
    }
    cur[tid] = start;
    __syncthreads();
    for (int i = beg + tid; i < end; i += 256) {
        int2 e = binned[i];
        int pos = atomicAdd(&cur[e.y & 255], 1);
        edge_src[pos] = e.x;
    }
}

// =============== MFMA fp16 GEMM, pre-scaled fp16 output ===============
// X[M][K] (fp32 or fp16), Wt[BN][K] fp16. XW16[row] = fp16((X@W)[row] * dinv[row]).
template <int BN, int K, typename AT>
__global__ __launch_bounds__(256) void k_gemm_mfma(
    const AT* __restrict__ X, const _Float16* __restrict__ Wt,
    const float* __restrict__ dinv, _Float16* __restrict__ XW16, int M)
{
    constexpr int BM = 64;
    constexpr int BK = 32;
    constexpr int NT = BN / 16;
    constexpr int LDK = BK + 8;   // 40 halfs = 80 B stride, 16B-aligned

    __shared__ __align__(16) _Float16 As[BM][LDK];
    __shared__ __align__(16) _Float16 Bs[BN][LDK];

    const int tid  = threadIdx.x;
    const int wave = tid >> 6;
    const int lane = tid & 63;
    const int m    = lane & 15;
    const int q    = lane >> 4;
    const int rb   = blockIdx.x * BM;

    f32x4 acc[NT];
#pragma unroll
    for (int t = 0; t < NT; t++) acc[t] = (f32x4){0.f, 0.f, 0.f, 0.f};

    for (int kt = 0; kt < K; kt += BK) {
        if (kt) __syncthreads();
        if constexpr (sizeof(AT) == 4) {
#pragma unroll
            for (int i = 0; i < BM * 8 / 256; i++) {
                int ch  = tid + i * 256;
                int row = ch >> 3;
                int c4  = ch & 7;
                int gr  = rb + row;
                float4 v = make_float4(0.f, 0.f, 0.f, 0.f);
                if (gr < M) v = *(const float4*)((const float*)X + (long)gr * K + kt + c4 * 4);
                _Float16* p = &As[row][c4 * 4];
                p[0] = (_Float16)v.x; p[1] = (_Float16)v.y;
                p[2] = (_Float16)v.z; p[3] = (_Float16)v.w;
            }
        } else {
            int row = tid >> 2;
            int c8  = tid & 3;
            int gr  = rb + row;
            uint4 v = make_uint4(0u, 0u, 0u, 0u);
            if (gr < M) v = *(const uint4*)((const _Float16*)X + (long)gr * K + kt + c8 * 8);
            *(uint4*)(&As[row][c8 * 8]) = v;
        }
#pragma unroll
        for (int i = 0; i < BN * 8 / 256; i++) {
            int ch = tid + i * 256;
            int n  = ch >> 3;
            int c4 = ch & 7;
            *(ushort4*)(&Bs[n][c4 * 4]) =
                *(const ushort4*)(Wt + (long)n * K + kt + c4 * 4);
        }
        __syncthreads();

        f16x8 af = *(const f16x8*)(&As[wave * 16 + m][q * 8]);
#pragma unroll
        for (int t = 0; t < NT; t++) {
            f16x8 bf = *(const f16x8*)(&Bs[t * 16 + m][q * 8]);
            acc[t] = __builtin_amdgcn_mfma_f32_16x16x32_f16(af, bf, acc[t], 0, 0, 0);
        }
    }

    int row0 = rb + wave * 16 + q * 4;
#pragma unroll
    for (int r = 0; r < 4; r++) {
        int row = row0 + r;
        if (row < M) {
            float di = dinv[row];
#pragma unroll
            for (int t = 0; t < NT; t++) {
                XW16[(long)row * BN + t * 16 + m] = (_Float16)(acc[t][r] * di);
            }
        }
    }
}

// =============== CSR gather-aggregation (pre-scaled fp16 table) ===============
// out[n] = act(bias + dinv[n] * (feat[n] + sum_{e in(n)} feat[src_e]))
template <int F, bool TANH, typename OutT>
__global__ __launch_bounds__(256) void k_agg_csr(const int* __restrict__ row_start,
                                                 const int* __restrict__ edge_src,
                                                 const _Float16* __restrict__ feat,
                                                 const float* __restrict__ bias,
                                                 const float* __restrict__ dinv,
                                                 OutT* __restrict__ out, int M) {
    constexpr int LPN = F / 8;          // lanes per node, 8 halfs (16B) each
    constexpr int NPB = 256 / LPN;
    int n = blockIdx.x * NPB + threadIdx.x / LPN;
    int c = threadIdx.x % LPN;
    if (n >= M) return;
    int beg = row_start[n], end = row_start[n + 1];

    f16x8 self = *(const f16x8*)(feat + (long)n * F + c * 8);
    float acc[8];
#pragma unroll
    for (int k = 0; k < 8; k++) acc[k] = (float)self[k];

    int j = beg;
    for (; j + 1 < end; j += 2) {
        int s0 = edge_src[j], s1 = edge_src[j + 1];
        f16x8 v0 = *(const f16x8*)(feat + (long)s0 * F + c * 8);
        f16x8 v1 = *(const f16x8*)(feat + (long)s1 * F + c * 8);
#pragma unroll
        for (int k = 0; k < 8; k++) acc[k] += (float)v0[k] + (float)v1[k];
    }
    if (j < end) {
        int s = edge_src[j];
        f16x8 v = *(const f16x8*)(feat + (long)s * F + c * 8);
#pragma unroll
        for (int k = 0; k < 8; k++) acc[k] += (float)v[k];
    }

    float di = dinv[n];
#pragma unroll
    for (int k = 0; k < 8; k++) acc[k] = bias[c * 8 + k] + di * acc[k];
    if (TANH) {
#pragma unroll
        for (int k = 0; k < 8; k++) acc[k] = tanhf(acc[k]);
    }
    if constexpr (sizeof(OutT) == 2) {
        f16x8 o;
#pragma unroll
        for (int k = 0; k < 8; k++) o[k] = (_Float16)acc[k];
        *(f16x8*)((_Float16*)out + (long)n * F + c * 8) = o;
    } else {
        float* p = (float*)out + (long)n * F + c * 8;
        *(float4*)(p)     = make_float4(acc[0], acc[1], acc[2], acc[3]);
        *(float4*)(p + 4) = make_float4(acc[4], acc[5], acc[6], acc[7]);
    }
}

extern "C" void kernel_launch(void* const* d_in, const int* in_sizes, int n_in,
                              void* d_out, int out_size, void* d_ws, size_t ws_size,
                              hipStream_t stream) {
    const float* x  = (const float*)d_in[0];
    const int*   ei = (const int*)d_in[1];
    const float* W1 = (const float*)d_in[2];
    const float* b1 = (const float*)d_in[3];
    const float* W2 = (const float*)d_in[4];
    const float* b2 = (const float*)d_in[5];
    float* out = (float*)d_out;

    const int M = in_sizes[0] / INDIM;   // 50000
    const int E = in_sizes[1] / 2;       // 800000
    const int* srcp = ei;
    const int* dstp = ei + E;

    const int Mp   = (M + 63) & ~63;         // even
    const int NBIN = (M + 255) >> BINSHIFT;  // 196 <= MAXBIN

    // workspace layout (keep int2 array 8B-aligned: all offsets even in ints)
    float*     dinv       = (float*)d_ws;
    int*       row_start  = (int*)(dinv + Mp);            // [M+1] <= Mp
    int*       bin_start  = row_start + Mp;               // [NBIN+1], padded 258
    int*       bin_cursor = bin_start + 258;              // [MAXBIN]
    int*       bin_counts = bin_cursor + MAXBIN;          // [MAXBIN]
    _Float16*  W1t        = (_Float16*)(bin_counts + MAXBIN);  // [HID][INDIM]
    _Float16*  W2t        = W1t + HID * INDIM;                 // [OUTD][HID]
    int2*      binned     = (int2*)(W2t + OUTD * HID);         // [E] {src,dst}
    int*       edge_src   = (int*)(binned + E);                // [E]
    _Float16*  xw16       = (_Float16*)(edge_src + E);         // [M][HID] pre-scaled
    _Float16*  h16        = xw16 + (long)M * HID;              // [M][HID]
    _Float16*  hw16       = xw16;                              // alias: xw dead after agg1

    const int NWE = (E + 2047) / 2048;   // edge-chunk workgroups

    // ---- setup + binned CSR build ----
    {
        int total = HID * INDIM + OUTD * HID + MAXBIN;
        k_setup<<<(total + 255) / 256, 256, 0, stream>>>(W1, W2, W1t, W2t, bin_counts);
    }
    k_hist<<<NWE, 256, 0, stream>>>(dstp, bin_counts, E);
    k_bscan<<<1, 256, 0, stream>>>(bin_counts, bin_start, bin_cursor, row_start, NBIN, M, E);
    k_binfill<<<NWE, 256, 0, stream>>>(srcp, dstp, bin_cursor, binned, E);
    k_csr<<<NBIN, 256, 0, stream>>>(binned, bin_start, row_start, dinv, edge_src, M);

    // ---- layer 1: xw16 = fp16((x@W1)*dinv) ; h16 = tanh(b1 + dinv*(self + edges)) ----
    k_gemm_mfma<HID, INDIM, float><<<(M + 63) / 64, 256, 0, stream>>>(x, W1t, dinv, xw16, M);
    k_agg_csr<HID, true, _Float16><<<(M + 15) / 16, 256, 0, stream>>>(row_start, edge_src, xw16, b1, dinv, h16, M);

    // ---- layer 2: hw16 = fp16((h@W2)*dinv) ; out = b2 + dinv*(self + edges) ----
    k_gemm_mfma<OUTD, HID, _Float16><<<(M + 63) / 64, 256, 0, stream>>>(h16, W2t, dinv, hw16, M);
    k_agg_csr<OUTD, false, float><<<(M + 31) / 32, 256, 0, stream>>>(row_start, edge_src, hw16, b2, dinv, out, M);
}